// Round 6
// baseline (123.637 us; speedup 1.0000x reference)
//
#include <hip/hip_runtime.h>
#include <hip/hip_bf16.h>

typedef float f32x4 __attribute__((ext_vector_type(4)));
typedef _Float16 f16x8 __attribute__((ext_vector_type(8)));
typedef unsigned int u32;

#define SQ   2048
#define HQ   16
#define HKV  4
#define DH   128
#define WIN  1024
#define QT   128
#define KT   64
#define WROW 36

#define AS1 __attribute__((address_space(1)))
#define AS3 __attribute__((address_space(3)))

__device__ __forceinline__ void gload16(const void* g, void* l) {
  __builtin_amdgcn_global_load_lds((const AS1 u32*)g, (AS3 u32*)l, 16, 0, 0);
}

// e = exp(30*tanh(s/sqrt(128)) - 30) == 2^(-86.5617/(2^(s*0.255070)+1))
__device__ __forceinline__ float swa_e(float s) {
  float u = __builtin_amdgcn_exp2f(s * 0.25507046054708916f);
  return __builtin_amdgcn_exp2f(-86.5617024533378f * __builtin_amdgcn_rcpf(u + 1.0f));
}

// ---- prep: K -> kf f16 row-chunk-swizzled; V -> vt f16 transposed+swizzled ----
__global__ __launch_bounds__(256)
void prep(const float* __restrict__ K, const float* __restrict__ V,
          _Float16* __restrict__ kf, _Float16* __restrict__ vt)
{
  const int t = blockIdx.x * 256 + threadIdx.x;
  const int NK = 2 * HKV * SQ * 16;   // 262144 threads for K
  if (t < NK) {
    const int p  = t & 15;
    const int s  = (t >> 4) & (SQ - 1);
    const int hk = (t >> 15) & 3;
    const int b  = t >> 17;
    const int c  = p ^ (s & 7);
    const float* src = K + (((size_t)b * SQ + s) * HKV + hk) * DH + c * 8;
    f32x4 x0 = *(const f32x4*)src;
    f32x4 x1 = *(const f32x4*)(src + 4);
    f16x8 o;
    #pragma unroll
    for (int j = 0; j < 4; ++j) { o[j] = (_Float16)x0[j]; o[4 + j] = (_Float16)x1[j]; }
    *(f16x8*)(kf + (((size_t)(b * HKV + hk)) * SQ + s) * DH + p * 8) = o;
  } else {
    const int u  = t - NK;
    const int p  = u & 7;
    const int d  = (u >> 3) & 127;
    const int tt = (u >> 10) & 31;
    const int hk = (u >> 15) & 3;
    const int b  = u >> 17;
    const int c  = p ^ (d & 7);
    f16x8 o;
    #pragma unroll
    for (int j = 0; j < 8; ++j) {
      const int s = tt * 64 + c * 8 + j;
      o[j] = (_Float16)V[(((size_t)b * SQ + s) * HKV + hk) * DH + d];
    }
    *(f16x8*)(vt + ((((size_t)(b * HKV + hk)) * 32 + tt) * DH + d) * 64 + p * 8) = o;
  }
}

__global__ __launch_bounds__(512, 6)
void swa_fwd(const float* __restrict__ Q, float* __restrict__ O,
             const _Float16* __restrict__ kf, const _Float16* __restrict__ vt)
{
  __shared__ _Float16 lK[KT * DH];      // 16KB; phase1: ping buffer
  __shared__ _Float16 lV[DH * KT];      // 16KB; phase1: pong buffer, phase2: V^T
  __shared__ _Float16 lW[8][16 * WROW]; // 9.2KB

  const int tid  = threadIdx.x;
  const int lane = tid & 63;
  const int wv   = tid >> 6;           // 0..7
  const int lm   = lane & 15;
  const int lg   = lane >> 4;

  // ---- XCD-pinned static mapping: stream=(b,hk) <-> XCD (bid%8); qt heavy-first ----
  const int bid    = blockIdx.x;
  const int stream = bid & 7;
  const int b      = stream >> 2;
  const int hk     = stream & 3;
  const int j      = bid >> 3;         // 0..63 within stream
  const int qt     = 15 - (j >> 2);    // heavy-first
  const int h      = hk * 4 + (j & 3);
  const int q0     = qt * QT;

  const _Float16* kfb = kf + ((size_t)(b * HKV + hk)) * SQ * DH;
  const _Float16* vtb = vt + ((size_t)(b * HKV + hk)) * 32 * DH * 64;

  // ---- Q fragments (A-layout): row=lm, k=lg*8+j per 32-wide kb ----
  f16x8 qa[4];
  {
    const int qrow = q0 + wv * 16 + lm;
    const float* qp = Q + (((size_t)b * SQ + qrow) * HQ + h) * DH;
    #pragma unroll
    for (int kb = 0; kb < 4; ++kb) {
      const float* p = qp + kb * 32 + lg * 8;
      f32x4 x0 = *(const f32x4*)p;
      f32x4 x1 = *(const f32x4*)(p + 4);
      f16x8 a;
      #pragma unroll
      for (int jj = 0; jj < 4; ++jj) { a[jj] = (_Float16)x0[jj]; a[4 + jj] = (_Float16)x1[jj]; }
      qa[kb] = a;
    }
  }

  const int kmin = (q0 - WIN) > 0 ? (q0 - WIN) : 0;   // multiple of 64
  const int nt   = (q0 + QT - kmin) / KT;             // 2..18
  const int qr0  = q0 + wv * 16 + lg * 4;

  // stage one 16KB tile: 2 rounds x 512 threads x 16B
  #define STAGE(dst, src) do {                                               \
    gload16((const char*)(src) + wv * 1024 + lane * 16,                      \
            (char*)(dst) + wv * 1024);                                       \
    gload16((const char*)(src) + 8192 + wv * 1024 + lane * 16,               \
            (char*)(dst) + 8192 + wv * 1024);                                \
  } while (0)

  // ================= phase 1: row sums Z (K ping-pong lK/lV) =================
  float zs[4] = {0.f, 0.f, 0.f, 0.f};
  {
    _Float16* cur = lK;
    _Float16* nxt = lV;
    STAGE(cur, kfb + (size_t)kmin * DH);
    __syncthreads();
    for (int t = 0; t < nt; ++t) {
      if (t + 1 < nt) STAGE(nxt, kfb + (size_t)(kmin + (t + 1) * KT) * DH);
      const int  kbase = kmin + t * KT;
      const bool peel  = ((q0 >= WIN) && (t <= 1)) || (t >= nt - 2);
      #pragma unroll
      for (int ks = 0; ks < 4; ++ks) {
        f32x4 acc = {0.f, 0.f, 0.f, 0.f};
        const int keyl = ks * 16 + lm;
        #pragma unroll
        for (int kb = 0; kb < 4; ++kb) {
          const int chunk = (kb * 4 + lg) ^ (keyl & 7);
          f16x8 bf = *(const f16x8*)((const char*)cur + keyl * 256 + chunk * 16);
          acc = __builtin_amdgcn_mfma_f32_16x16x32_f16(qa[kb], bf, acc, 0, 0, 0);
        }
        if (peel) {
          const int key = kbase + keyl;
          #pragma unroll
          for (int r = 0; r < 4; ++r) {
            const int qr = qr0 + r;
            const bool ok = (key <= qr) && (key >= qr - WIN);
            zs[r] += ok ? swa_e(acc[r]) : 0.f;
          }
        } else {
          #pragma unroll
          for (int r = 0; r < 4; ++r) zs[r] += swa_e(acc[r]);
        }
      }
      __syncthreads();
      _Float16* tmp = cur; cur = nxt; nxt = tmp;
    }
  }

  // ---- Z reduce; rz = 1.06/Z; sthr = exact survivor threshold in s-space ----
  float rz[4], sthr[4];
  #pragma unroll
  for (int r = 0; r < 4; ++r) {
    float z = zs[r];
    z += __shfl_xor(z, 1);
    z += __shfl_xor(z, 2);
    z += __shfl_xor(z, 4);
    z += __shfl_xor(z, 8);
    rz[r] = 1.06f / z;
    // survivor: e > t0 = 0.03*Z/1.06;  e = 2^(c2/(u+1)), u = 2^(c1*s)
    float lt = __log2f(0.0283018868f * z);
    float A  = -86.5617024533378f / lt - 1.0f;
    float sv = 3.9204912f * __log2f(A) - 0.05f;   // conservative margin
    sv = (lt >= 0.f) ? 1e30f : sv;
    sv = (lt <= -86.5617f) ? -1e30f : sv;
    sthr[r] = sv;
  }

  // ================= phase 2: weights + PV =================
  f32x4 oacc[8];
  #pragma unroll
  for (int i = 0; i < 8; ++i) oacc[i] = (f32x4){0.f, 0.f, 0.f, 0.f};

  for (int t = 0; t < nt; ++t) {
    const int kbase = kmin + t * KT;
    __syncthreads();
    STAGE(lK, kfb + (size_t)kbase * DH);
    STAGE(lV, vtb + (size_t)(kbase >> 6) * (DH * 64));
    __syncthreads();

    const bool peel = ((q0 >= WIN) && (t <= 1)) || (t >= nt - 2);

    #pragma unroll
    for (int half = 0; half < 2; ++half) {
      #pragma unroll
      for (int ks = 0; ks < 2; ++ks) {
        f32x4 acc = {0.f, 0.f, 0.f, 0.f};
        const int keyl = (half * 2 + ks) * 16 + lm;
        #pragma unroll
        for (int kb = 0; kb < 4; ++kb) {
          const int chunk = (kb * 4 + lg) ^ (keyl & 7);
          f16x8 bf = *(const f16x8*)((const char*)lK + keyl * 256 + chunk * 16);
          acc = __builtin_amdgcn_mfma_f32_16x16x32_f16(qa[kb], bf, acc, 0, 0, 0);
        }
        const int key = kbase + keyl;
        #pragma unroll
        for (int r = 0; r < 4; ++r) {
          float w = 0.f;
          if (__any(acc[r] > sthr[r])) {
            float e = swa_e(acc[r]);
            w = fminf(fmaxf(fmaf(e, rz[r], -0.03f), 0.f), 1.f);
            if (peel) {
              const int qr = qr0 + r;
              const bool ok = (key <= qr) && (key >= qr - WIN);
              w = ok ? w : 0.f;
            }
          }
          lW[wv][(lg * 4 + r) * WROW + ks * 16 + lm] = (_Float16)w;
        }
      }
      // PV: A = W (row-major, per-wave), B = V^T rows from swizzled LDS
      const f16x8 af = *(const f16x8*)&lW[wv][lm * WROW + lg * 8];
      #pragma unroll
      for (int dt = 0; dt < 8; ++dt) {
        const int d = dt * 16 + lm;
        const int chunk = (half * 4 + lg) ^ (d & 7);
        f16x8 bf = *(const f16x8*)((const char*)lV + d * 128 + chunk * 16);
        oacc[dt] = __builtin_amdgcn_mfma_f32_16x16x32_f16(af, bf, oacc[dt], 0, 0, 0);
      }
    }
  }

  // ---- epilogue: D-layout (col=lm is d, row=lg*4+r) -> fp32 out ----
  #pragma unroll
  for (int r = 0; r < 4; ++r) {
    float* op = O + (((size_t)b * SQ + (qr0 + r)) * HQ + h) * DH;
    #pragma unroll
    for (int dt = 0; dt < 8; ++dt) op[dt * 16 + lm] = oacc[dt][r];
  }
  #undef STAGE
}

extern "C" void kernel_launch(void* const* d_in, const int* in_sizes, int n_in,
                              void* d_out, int out_size, void* d_ws, size_t ws_size,
                              hipStream_t stream) {
  const float* q = (const float*)d_in[0];
  const float* k = (const float*)d_in[1];
  const float* v = (const float*)d_in[2];
  float* o = (float*)d_out;

  _Float16* kf = (_Float16*)d_ws;
  _Float16* vt = kf + (size_t)2 * HKV * SQ * DH;   // 2,097,152 elems each

  hipLaunchKernelGGL(prep, dim3(2048), dim3(256), 0, stream, k, v, kf, vt);
  hipLaunchKernelGGL(swa_fwd, dim3(512), dim3(512), 0, stream, q, o, kf, vt);
}

// Round 7
// 97.038 us; speedup vs baseline: 1.2741x; 1.2741x over previous
//
#include <hip/hip_runtime.h>
#include <hip/hip_bf16.h>

typedef float f32x4 __attribute__((ext_vector_type(4)));
typedef _Float16 f16x8 __attribute__((ext_vector_type(8)));
typedef unsigned int u32;

#define SQ   2048
#define HQ   16
#define HKV  4
#define DH   128
#define WIN  1024
#define QT   128
#define KT   64
#define WROW 36

#define AS1 __attribute__((address_space(1)))
#define AS3 __attribute__((address_space(3)))

__device__ __forceinline__ void gload16(const void* g, void* l) {
  __builtin_amdgcn_global_load_lds((const AS1 u32*)g, (AS3 u32*)l, 16, 0, 0);
}

// e = exp(30*tanh(s/sqrt(128)) - 30) == 2^(-86.5617/(2^(s*0.255070)+1))
__device__ __forceinline__ float swa_e(float s) {
  float u = __builtin_amdgcn_exp2f(s * 0.25507046054708916f);
  return __builtin_amdgcn_exp2f(-86.5617024533378f * __builtin_amdgcn_rcpf(u + 1.0f));
}

// ---- prep: K -> kf f16 row-chunk-swizzled; V -> vt f16 transposed+swizzled ----
__global__ __launch_bounds__(256)
void prep(const float* __restrict__ K, const float* __restrict__ V,
          _Float16* __restrict__ kf, _Float16* __restrict__ vt)
{
  const int t = blockIdx.x * 256 + threadIdx.x;
  const int NK = 2 * HKV * SQ * 16;   // 262144 threads for K
  if (t < NK) {
    const int p  = t & 15;
    const int s  = (t >> 4) & (SQ - 1);
    const int hk = (t >> 15) & 3;
    const int b  = t >> 17;
    const int c  = p ^ (s & 7);
    const float* src = K + (((size_t)b * SQ + s) * HKV + hk) * DH + c * 8;
    f32x4 x0 = *(const f32x4*)src;
    f32x4 x1 = *(const f32x4*)(src + 4);
    f16x8 o;
    #pragma unroll
    for (int j = 0; j < 4; ++j) { o[j] = (_Float16)x0[j]; o[4 + j] = (_Float16)x1[j]; }
    *(f16x8*)(kf + (((size_t)(b * HKV + hk)) * SQ + s) * DH + p * 8) = o;
  } else {
    const int u  = t - NK;
    const int p  = u & 7;
    const int d  = (u >> 3) & 127;
    const int tt = (u >> 10) & 31;
    const int hk = (u >> 15) & 3;
    const int b  = u >> 17;
    const int c  = p ^ (d & 7);
    f16x8 o;
    #pragma unroll
    for (int j = 0; j < 8; ++j) {
      const int s = tt * 64 + c * 8 + j;
      o[j] = (_Float16)V[(((size_t)b * SQ + s) * HKV + hk) * DH + d];
    }
    *(f16x8*)(vt + ((((size_t)(b * HKV + hk)) * 32 + tt) * DH + d) * 64 + p * 8) = o;
  }
}

__global__ __launch_bounds__(512, 4)
void swa_fwd(const float* __restrict__ Q, float* __restrict__ O,
             const _Float16* __restrict__ kf, const _Float16* __restrict__ vt)
{
  __shared__ _Float16 lK2[2][KT * DH];  // 32KB double-buffered K
  __shared__ _Float16 lV2[2][KT * DH];  // 32KB double-buffered V^T
  __shared__ _Float16 lW[8][16 * WROW]; // 9.2KB

  const int tid  = threadIdx.x;
  const int lane = tid & 63;
  const int wv   = tid >> 6;           // 0..7
  const int lm   = lane & 15;
  const int lg   = lane >> 4;

  // ---- XCD-pinned static mapping: stream=(b,hk) <-> XCD (bid%8); qt heavy-first ----
  const int bid    = blockIdx.x;
  const int stream = bid & 7;
  const int b      = stream >> 2;
  const int hk     = stream & 3;
  const int j      = bid >> 3;         // 0..63 within stream
  const int qt     = 15 - (j >> 2);    // heavy-first
  const int h      = hk * 4 + (j & 3);
  const int q0     = qt * QT;

  const _Float16* kfb = kf + ((size_t)(b * HKV + hk)) * SQ * DH;
  const _Float16* vtb = vt + ((size_t)(b * HKV + hk)) * 32 * DH * 64;

  // ---- Q fragments (A-layout): row=lm, k=lg*8+j per 32-wide kb ----
  f16x8 qa[4];
  {
    const int qrow = q0 + wv * 16 + lm;
    const float* qp = Q + (((size_t)b * SQ + qrow) * HQ + h) * DH;
    #pragma unroll
    for (int kb = 0; kb < 4; ++kb) {
      const float* p = qp + kb * 32 + lg * 8;
      f32x4 x0 = *(const f32x4*)p;
      f32x4 x1 = *(const f32x4*)(p + 4);
      f16x8 a;
      #pragma unroll
      for (int jj = 0; jj < 4; ++jj) { a[jj] = (_Float16)x0[jj]; a[4 + jj] = (_Float16)x1[jj]; }
      qa[kb] = a;
    }
  }

  const int kmin = (q0 - WIN) > 0 ? (q0 - WIN) : 0;   // multiple of 64
  const int nt   = (q0 + QT - kmin) / KT;             // 2..18
  const int qr0  = q0 + wv * 16 + lg * 4;

  // stage one 16KB tile: 2 rounds x 512 threads x 16B
  #define STAGE(dst, src) do {                                               \
    gload16((const char*)(src) + wv * 1024 + lane * 16,                      \
            (char*)(dst) + wv * 1024);                                       \
    gload16((const char*)(src) + 8192 + wv * 1024 + lane * 16,               \
            (char*)(dst) + 8192 + wv * 1024);                                \
  } while (0)

  // ================= phase 1: row sums Z (K ping-pong lK2[0]/lK2[1]) =================
  float zs[4] = {0.f, 0.f, 0.f, 0.f};
  {
    STAGE(lK2[0], kfb + (size_t)kmin * DH);
    __syncthreads();
    for (int t = 0; t < nt; ++t) {
      if (t + 1 < nt) STAGE(lK2[(t + 1) & 1], kfb + (size_t)(kmin + (t + 1) * KT) * DH);
      const _Float16* cur = lK2[t & 1];
      const int  kbase = kmin + t * KT;
      const bool peel  = ((q0 >= WIN) && (t <= 1)) || (t >= nt - 2);
      #pragma unroll
      for (int ks = 0; ks < 4; ++ks) {
        f32x4 acc = {0.f, 0.f, 0.f, 0.f};
        const int keyl = ks * 16 + lm;
        #pragma unroll
        for (int kb = 0; kb < 4; ++kb) {
          const int chunk = (kb * 4 + lg) ^ (keyl & 7);
          f16x8 bf = *(const f16x8*)((const char*)cur + keyl * 256 + chunk * 16);
          acc = __builtin_amdgcn_mfma_f32_16x16x32_f16(qa[kb], bf, acc, 0, 0, 0);
        }
        if (peel) {
          const int key = kbase + keyl;
          #pragma unroll
          for (int r = 0; r < 4; ++r) {
            const int qr = qr0 + r;
            const bool ok = (key <= qr) && (key >= qr - WIN);
            zs[r] += ok ? swa_e(acc[r]) : 0.f;
          }
        } else {
          #pragma unroll
          for (int r = 0; r < 4; ++r) zs[r] += swa_e(acc[r]);
        }
      }
      __syncthreads();
    }
  }

  // ---- Z reduce; rz = 1.06/Z; sthr = exact survivor threshold in s-space ----
  float rz[4], sthr[4];
  #pragma unroll
  for (int r = 0; r < 4; ++r) {
    float z = zs[r];
    z += __shfl_xor(z, 1);
    z += __shfl_xor(z, 2);
    z += __shfl_xor(z, 4);
    z += __shfl_xor(z, 8);
    rz[r] = 1.06f / z;
    // survivor: e > t0 = 0.03*Z/1.06;  e = 2^(c2/(u+1)), u = 2^(c1*s)
    float lt = __log2f(0.0283018868f * z);
    float A  = -86.5617024533378f / lt - 1.0f;
    float sv = 3.9204912f * __log2f(A) - 0.05f;   // conservative margin
    sv = (lt >= 0.f) ? 1e30f : sv;
    sv = (lt <= -86.5617f) ? -1e30f : sv;
    sthr[r] = sv;
  }

  // ================= phase 2: weights + PV (double-buffered K+V) =================
  f32x4 oacc[8];
  #pragma unroll
  for (int i = 0; i < 8; ++i) oacc[i] = (f32x4){0.f, 0.f, 0.f, 0.f};

  STAGE(lK2[0], kfb + (size_t)kmin * DH);
  STAGE(lV2[0], vtb + (size_t)(kmin >> 6) * (DH * 64));
  __syncthreads();

  for (int t = 0; t < nt; ++t) {
    if (t + 1 < nt) {
      const int kn = kmin + (t + 1) * KT;
      STAGE(lK2[(t + 1) & 1], kfb + (size_t)kn * DH);
      STAGE(lV2[(t + 1) & 1], vtb + (size_t)(kn >> 6) * (DH * 64));
    }
    const _Float16* curK = lK2[t & 1];
    const _Float16* curV = lV2[t & 1];
    const int  kbase = kmin + t * KT;
    const bool peel  = ((q0 >= WIN) && (t <= 1)) || (t >= nt - 2);

    #pragma unroll
    for (int half = 0; half < 2; ++half) {
      #pragma unroll
      for (int ks = 0; ks < 2; ++ks) {
        f32x4 acc = {0.f, 0.f, 0.f, 0.f};
        const int keyl = (half * 2 + ks) * 16 + lm;
        #pragma unroll
        for (int kb = 0; kb < 4; ++kb) {
          const int chunk = (kb * 4 + lg) ^ (keyl & 7);
          f16x8 bf = *(const f16x8*)((const char*)curK + keyl * 256 + chunk * 16);
          acc = __builtin_amdgcn_mfma_f32_16x16x32_f16(qa[kb], bf, acc, 0, 0, 0);
        }
        const int key = kbase + keyl;
        #pragma unroll
        for (int r = 0; r < 4; ++r) {
          float w = 0.f;
          if (__any(acc[r] > sthr[r])) {
            float e = swa_e(acc[r]);
            w = fminf(fmaxf(fmaf(e, rz[r], -0.03f), 0.f), 1.f);
            if (peel) {
              const int qr = qr0 + r;
              const bool ok = (key <= qr) && (key >= qr - WIN);
              w = ok ? w : 0.f;
            }
          }
          lW[wv][(lg * 4 + r) * WROW + ks * 16 + lm] = (_Float16)w;
        }
      }
      // PV: A = W (row-major, per-wave), B = V^T rows from swizzled LDS
      const f16x8 af = *(const f16x8*)&lW[wv][lm * WROW + lg * 8];
      #pragma unroll
      for (int dt = 0; dt < 8; ++dt) {
        const int d = dt * 16 + lm;
        const int chunk = (half * 4 + lg) ^ (d & 7);
        f16x8 bf = *(const f16x8*)((const char*)curV + d * 128 + chunk * 16);
        oacc[dt] = __builtin_amdgcn_mfma_f32_16x16x32_f16(af, bf, oacc[dt], 0, 0, 0);
      }
    }
    __syncthreads();
  }

  // ---- epilogue: D-layout (col=lm is d, row=lg*4+r) -> fp32 out ----
  #pragma unroll
  for (int r = 0; r < 4; ++r) {
    float* op = O + (((size_t)b * SQ + (qr0 + r)) * HQ + h) * DH;
    #pragma unroll
    for (int dt = 0; dt < 8; ++dt) op[dt * 16 + lm] = oacc[dt][r];
  }
  #undef STAGE
}

extern "C" void kernel_launch(void* const* d_in, const int* in_sizes, int n_in,
                              void* d_out, int out_size, void* d_ws, size_t ws_size,
                              hipStream_t stream) {
  const float* q = (const float*)d_in[0];
  const float* k = (const float*)d_in[1];
  const float* v = (const float*)d_in[2];
  float* o = (float*)d_out;

  _Float16* kf = (_Float16*)d_ws;
  _Float16* vt = kf + (size_t)2 * HKV * SQ * DH;   // 2,097,152 elems each

  hipLaunchKernelGGL(prep, dim3(2048), dim3(256), 0, stream, k, v, kf, vt);
  hipLaunchKernelGGL(swa_fwd, dim3(512), dim3(512), 0, stream, q, o, kf, vt);
}

// Round 8
// 88.869 us; speedup vs baseline: 1.3912x; 1.0919x over previous
//
#include <hip/hip_runtime.h>
#include <hip/hip_bf16.h>

typedef float f32x4 __attribute__((ext_vector_type(4)));
typedef _Float16 f16x8 __attribute__((ext_vector_type(8)));
typedef unsigned int u32;

#define SQ   2048
#define HQ   16
#define HKV  4
#define DH   128
#define WIN  1024
#define QT   64
#define KT   64
#define WROW 36

#define AS1 __attribute__((address_space(1)))
#define AS3 __attribute__((address_space(3)))

__device__ __forceinline__ void gload16(const void* g, void* l) {
  __builtin_amdgcn_global_load_lds((const AS1 u32*)g, (AS3 u32*)l, 16, 0, 0);
}

// e = exp(30*tanh(s/sqrt(128)) - 30) == 2^(-86.5617/(2^(s*0.255070)+1))
__device__ __forceinline__ float swa_e(float s) {
  float u = __builtin_amdgcn_exp2f(s * 0.25507046054708916f);
  return __builtin_amdgcn_exp2f(-86.5617024533378f * __builtin_amdgcn_rcpf(u + 1.0f));
}

// ---- prep: K -> kf f16 row-chunk-swizzled [b][hk][s][d];
//            V -> vt f16 [b][hk][t32][d][key32] contiguous 8KB sub-tiles ----
__global__ __launch_bounds__(256)
void prep(const float* __restrict__ K, const float* __restrict__ V,
          _Float16* __restrict__ kf, _Float16* __restrict__ vt)
{
  const int t = blockIdx.x * 256 + threadIdx.x;
  const int NK = 2 * HKV * SQ * 16;   // 262144 threads for K
  if (t < NK) {
    const int p  = t & 15;
    const int s  = (t >> 4) & (SQ - 1);
    const int hk = (t >> 15) & 3;
    const int b  = t >> 17;
    const int c  = p ^ (s & 7);
    const float* src = K + (((size_t)b * SQ + s) * HKV + hk) * DH + c * 8;
    f32x4 x0 = *(const f32x4*)src;
    f32x4 x1 = *(const f32x4*)(src + 4);
    f16x8 o;
    #pragma unroll
    for (int j = 0; j < 4; ++j) { o[j] = (_Float16)x0[j]; o[4 + j] = (_Float16)x1[j]; }
    *(f16x8*)(kf + (((size_t)(b * HKV + hk)) * SQ + s) * DH + p * 8) = o;
  } else {
    const int u   = t - NK;                 // 262144 threads for V
    const int p   = u & 3;                  // 8-key group within 32
    const int d   = (u >> 2) & 127;
    const int t32 = (u >> 9) & 63;
    const int hk  = (u >> 15) & 3;
    const int b   = u >> 17;
    f16x8 o;
    #pragma unroll
    for (int j = 0; j < 8; ++j) {
      const int s = t32 * 32 + p * 8 + j;
      o[j] = (_Float16)V[(((size_t)b * SQ + s) * HKV + hk) * DH + d];
    }
    *(f16x8*)(vt + ((((size_t)(b * HKV + hk)) * 64 + t32) * DH + d) * 32 + p * 8) = o;
  }
}

__global__ __launch_bounds__(256, 4)
void swa_fwd(const float* __restrict__ Q, float* __restrict__ O,
             const _Float16* __restrict__ kf, const _Float16* __restrict__ vt)
{
  __shared__ _Float16 lbuf[16384];       // 32KB = 4 x 8KB sub-buffers
  __shared__ _Float16 lW[4][16 * WROW];  // 4.6KB

  const int tid  = threadIdx.x;
  const int lane = tid & 63;
  const int wv   = tid >> 6;             // 0..3
  const int lm   = lane & 15;
  const int lg   = lane >> 4;

  // ---- XCD-pinned + CU-balanced quad mapping ----
  // stream=(b,hk)<->XCD via bid%8; same-CU j's {c,c+32,c+64,c+96} get quad
  // (31-i, 16+i, 15-i, i): sum nt = 51 for all i.
  const int bid    = blockIdx.x;
  const int stream = bid & 7;
  const int b      = stream >> 2;
  const int hk     = stream & 3;
  const int j      = bid >> 3;           // 0..127
  const int c      = j & 31;
  const int slot   = j >> 5;             // 0..3 (0 = heaviest, dispatched first)
  const int i      = c >> 2;             // 0..7
  const int hs     = c & 3;
  const int qt     = (slot == 0) ? (31 - i) : (slot == 1) ? (16 + i)
                   : (slot == 2) ? (15 - i) : i;
  const int h      = hk * 4 + hs;
  const int q0     = qt * QT;

  const _Float16* kfb = kf + ((size_t)(b * HKV + hk)) * SQ * DH;
  const char*     vtb = (const char*)(vt + ((size_t)(b * HKV + hk)) * 64 * DH * 32);

  // ---- Q fragments (A-layout): row=lm, k=lg*8+j per 32-wide kb ----
  f16x8 qa[4];
  {
    const int qrow = q0 + wv * 16 + lm;
    const float* qp = Q + (((size_t)b * SQ + qrow) * HQ + h) * DH;
    #pragma unroll
    for (int kb = 0; kb < 4; ++kb) {
      const float* p = qp + kb * 32 + lg * 8;
      f32x4 x0 = *(const f32x4*)p;
      f32x4 x1 = *(const f32x4*)(p + 4);
      f16x8 a;
      #pragma unroll
      for (int jj = 0; jj < 4; ++jj) { a[jj] = (_Float16)x0[jj]; a[4 + jj] = (_Float16)x1[jj]; }
      qa[kb] = a;
    }
  }

  const int kmin = (q0 - WIN) > 0 ? (q0 - WIN) : 0;   // multiple of 64
  const int nt   = (q0 + QT - kmin) / KT;             // 1..17
  const int qr0  = q0 + wv * 16 + lg * 4;

  // stage 16KB (64-key K tile) / 8KB (32-key K or V tile); 256 threads x 16B
  #define STAGE16K(dstb, src) do {                                           \
    _Pragma("unroll")                                                        \
    for (int r4 = 0; r4 < 4; ++r4)                                           \
      gload16((const char*)(src) + r4 * 4096 + wv * 1024 + lane * 16,        \
              (char*)lbuf + (dstb) + r4 * 4096 + wv * 1024);                 \
  } while (0)
  #define STAGE8K(dstb, src) do {                                            \
    _Pragma("unroll")                                                        \
    for (int r2 = 0; r2 < 2; ++r2)                                           \
      gload16((const char*)(src) + r2 * 4096 + wv * 1024 + lane * 16,        \
              (char*)lbuf + (dstb) + r2 * 4096 + wv * 1024);                 \
  } while (0)

  // ================= phase 1: row sums Z (KT=64 K ping-pong) =================
  float zs[4] = {0.f, 0.f, 0.f, 0.f};
  {
    STAGE16K(0, kfb + (size_t)kmin * DH);
    __syncthreads();
    for (int t = 0; t < nt; ++t) {
      if (t + 1 < nt) STAGE16K(((t + 1) & 1) * 16384, kfb + (size_t)(kmin + (t + 1) * KT) * DH);
      const char* cur  = (const char*)lbuf + (t & 1) * 16384;
      const int  kbase = kmin + t * KT;
      const bool peel  = (t == 0 && q0 >= WIN) || (t == nt - 1);
      #pragma unroll
      for (int ks = 0; ks < 4; ++ks) {
        f32x4 acc = {0.f, 0.f, 0.f, 0.f};
        const int keyl = ks * 16 + lm;
        #pragma unroll
        for (int kb = 0; kb < 4; ++kb) {
          const int chunk = (kb * 4 + lg) ^ (keyl & 7);
          f16x8 bf = *(const f16x8*)(cur + keyl * 256 + chunk * 16);
          acc = __builtin_amdgcn_mfma_f32_16x16x32_f16(qa[kb], bf, acc, 0, 0, 0);
        }
        if (peel) {
          const int key = kbase + keyl;
          #pragma unroll
          for (int r = 0; r < 4; ++r) {
            const int qr = qr0 + r;
            const bool ok = (key <= qr) && (key >= qr - WIN);
            zs[r] += ok ? swa_e(acc[r]) : 0.f;
          }
        } else {
          #pragma unroll
          for (int r = 0; r < 4; ++r) zs[r] += swa_e(acc[r]);
        }
      }
      __syncthreads();
    }
  }

  // ---- Z reduce; rz = 1.06/Z; sthr = survivor threshold in s-space ----
  float rz[4], sthr[4];
  #pragma unroll
  for (int r = 0; r < 4; ++r) {
    float z = zs[r];
    z += __shfl_xor(z, 1);
    z += __shfl_xor(z, 2);
    z += __shfl_xor(z, 4);
    z += __shfl_xor(z, 8);
    rz[r] = 1.06f / z;
    float lt = __log2f(0.0283018868f * z);
    float A  = -86.5617024533378f / lt - 1.0f;
    float sv = 3.9204912f * __log2f(A) - 0.05f;   // conservative margin
    sv = (lt >= 0.f) ? 1e30f : sv;
    sv = (lt <= -86.5617f) ? -1e30f : sv;
    sthr[r] = sv;
  }

  // ====== phase 2: weights + PV, KT=32 double-buffered K and V ======
  // lbuf bytes: K0 @0, K1 @8192, V0 @16384, V1 @24576
  f32x4 oacc[8];
  #pragma unroll
  for (int ii = 0; ii < 8; ++ii) oacc[ii] = (f32x4){0.f, 0.f, 0.f, 0.f};

  const int nt2 = (q0 + QT - kmin) >> 5;   // 32-key sub-tiles
  STAGE8K(0,     kfb + (size_t)kmin * DH);
  STAGE8K(16384, vtb + (size_t)(kmin >> 5) * 8192);
  __syncthreads();

  for (int t2 = 0; t2 < nt2; ++t2) {
    if (t2 + 1 < nt2) {
      const int kn = kmin + (t2 + 1) * 32;
      STAGE8K(((t2 + 1) & 1) * 8192,         kfb + (size_t)kn * DH);
      STAGE8K(16384 + ((t2 + 1) & 1) * 8192, vtb + (size_t)(kn >> 5) * 8192);
    }
    const char* curK = (const char*)lbuf + (t2 & 1) * 8192;
    const char* curV = (const char*)lbuf + 16384 + (t2 & 1) * 8192;
    const int  kbase = kmin + t2 * 32;
    const bool peel  = ((q0 >= WIN) && (t2 <= 1)) || (t2 >= nt2 - 2);

    #pragma unroll
    for (int ks = 0; ks < 2; ++ks) {
      f32x4 acc = {0.f, 0.f, 0.f, 0.f};
      const int keyl = ks * 16 + lm;
      #pragma unroll
      for (int kb = 0; kb < 4; ++kb) {
        const int chunk = (kb * 4 + lg) ^ (keyl & 7);
        f16x8 bf = *(const f16x8*)(curK + keyl * 256 + chunk * 16);
        acc = __builtin_amdgcn_mfma_f32_16x16x32_f16(qa[kb], bf, acc, 0, 0, 0);
      }
      const int key = kbase + keyl;
      #pragma unroll
      for (int r = 0; r < 4; ++r) {
        float w = 0.f;
        if (__any(acc[r] > sthr[r])) {
          float e = swa_e(acc[r]);
          w = fminf(fmaxf(fmaf(e, rz[r], -0.03f), 0.f), 1.f);
          if (peel) {
            const int qr = qr0 + r;
            const bool ok = (key <= qr) && (key >= qr - WIN);
            w = ok ? w : 0.f;
          }
        }
        lW[wv][(lg * 4 + r) * WROW + ks * 16 + lm] = (_Float16)w;
      }
    }
    // PV over 32 keys: A = W rows (keys 0..31), B = V sub-tile rows [d][32]
    const f16x8 af = *(const f16x8*)&lW[wv][lm * WROW + lg * 8];
    #pragma unroll
    for (int dt = 0; dt < 8; ++dt) {
      const int d = dt * 16 + lm;
      f16x8 bf = *(const f16x8*)(curV + d * 64 + lg * 16);
      oacc[dt] = __builtin_amdgcn_mfma_f32_16x16x32_f16(af, bf, oacc[dt], 0, 0, 0);
    }
    __syncthreads();
  }

  // ---- epilogue: D-layout (col=lm is d, row=lg*4+r) -> fp32 out ----
  #pragma unroll
  for (int r = 0; r < 4; ++r) {
    float* op = O + (((size_t)b * SQ + (qr0 + r)) * HQ + h) * DH;
    #pragma unroll
    for (int dt = 0; dt < 8; ++dt) op[dt * 16 + lm] = oacc[dt][r];
  }
  #undef STAGE16K
  #undef STAGE8K
}

extern "C" void kernel_launch(void* const* d_in, const int* in_sizes, int n_in,
                              void* d_out, int out_size, void* d_ws, size_t ws_size,
                              hipStream_t stream) {
  const float* q = (const float*)d_in[0];
  const float* k = (const float*)d_in[1];
  const float* v = (const float*)d_in[2];
  float* o = (float*)d_out;

  _Float16* kf = (_Float16*)d_ws;
  _Float16* vt = kf + (size_t)2 * HKV * SQ * DH;   // 2,097,152 elems each

  hipLaunchKernelGGL(prep, dim3(2048), dim3(256), 0, stream, k, v, kf, vt);
  hipLaunchKernelGGL(swa_fwd, dim3(1024), dim3(256), 0, stream, q, o, kf, vt);
}

// Round 9
// 87.484 us; speedup vs baseline: 1.4133x; 1.0158x over previous
//
#include <hip/hip_runtime.h>
#include <hip/hip_bf16.h>

typedef float f32x4 __attribute__((ext_vector_type(4)));
typedef _Float16 f16x8 __attribute__((ext_vector_type(8)));
typedef unsigned int u32;

#define SQ   2048
#define HQ   16
#define HKV  4
#define DH   128
#define WIN  1024
#define QT   64
#define KT   64
#define WROW 36

#define AS1 __attribute__((address_space(1)))
#define AS3 __attribute__((address_space(3)))

__device__ __forceinline__ void gload16(const void* g, void* l) {
  __builtin_amdgcn_global_load_lds((const AS1 u32*)g, (AS3 u32*)l, 16, 0, 0);
}

// e = exp(30*tanh(s/sqrt(128)) - 30) == 2^(-86.5617/(2^(s*0.255070)+1))
__device__ __forceinline__ float swa_e(float s) {
  float u = __builtin_amdgcn_exp2f(s * 0.25507046054708916f);
  return __builtin_amdgcn_exp2f(-86.5617024533378f * __builtin_amdgcn_rcpf(u + 1.0f));
}

// ---- prep: K -> kf f16 row-chunk-swizzled [b][hk][s][d];
//            V -> vt f16 [b][hk][t32][d][key32], chunk c stored at c^((d>>1)&3) ----
__global__ __launch_bounds__(256)
void prep(const float* __restrict__ K, const float* __restrict__ V,
          _Float16* __restrict__ kf, _Float16* __restrict__ vt)
{
  const int t = blockIdx.x * 256 + threadIdx.x;
  const int NK = 2 * HKV * SQ * 16;   // 262144 threads for K
  if (t < NK) {
    const int p  = t & 15;
    const int s  = (t >> 4) & (SQ - 1);
    const int hk = (t >> 15) & 3;
    const int b  = t >> 17;
    const int c  = p ^ (s & 7);
    const float* src = K + (((size_t)b * SQ + s) * HKV + hk) * DH + c * 8;
    f32x4 x0 = *(const f32x4*)src;
    f32x4 x1 = *(const f32x4*)(src + 4);
    f16x8 o;
    #pragma unroll
    for (int j = 0; j < 4; ++j) { o[j] = (_Float16)x0[j]; o[4 + j] = (_Float16)x1[j]; }
    *(f16x8*)(kf + (((size_t)(b * HKV + hk)) * SQ + s) * DH + p * 8) = o;
  } else {
    const int u   = t - NK;                 // 262144 threads for V
    const int p   = u & 3;                  // PHYSICAL 8-key chunk within 32
    const int d   = (u >> 2) & 127;
    const int t32 = (u >> 9) & 63;
    const int hk  = (u >> 15) & 3;
    const int b   = u >> 17;
    const int c   = p ^ ((d >> 1) & 3);     // logical chunk stored at physical p
    f16x8 o;
    #pragma unroll
    for (int j = 0; j < 8; ++j) {
      const int s = t32 * 32 + c * 8 + j;
      o[j] = (_Float16)V[(((size_t)b * SQ + s) * HKV + hk) * DH + d];
    }
    *(f16x8*)(vt + ((((size_t)(b * HKV + hk)) * 64 + t32) * DH + d) * 32 + p * 8) = o;
  }
}

__global__ __launch_bounds__(256, 4)
void swa_fwd(const float* __restrict__ Q, float* __restrict__ O,
             const _Float16* __restrict__ kf, const _Float16* __restrict__ vt)
{
  __shared__ _Float16 lbuf[16384];       // 32KB = 4 x 8KB sub-buffers
  __shared__ _Float16 lW[4][16 * WROW];  // 4.6KB

  const int tid  = threadIdx.x;
  const int lane = tid & 63;
  const int wv   = tid >> 6;             // 0..3
  const int lm   = lane & 15;
  const int lg   = lane >> 4;

  // ---- XCD-pinned + CU-balanced quad mapping ----
  const int bid    = blockIdx.x;
  const int stream = bid & 7;
  const int b      = stream >> 2;
  const int hk     = stream & 3;
  const int j      = bid >> 3;           // 0..127
  const int c      = j & 31;
  const int slot   = j >> 5;             // 0..3 (0 = heaviest, dispatched first)
  const int i      = c >> 2;             // 0..7
  const int hs     = c & 3;
  const int qt     = (slot == 0) ? (31 - i) : (slot == 1) ? (16 + i)
                   : (slot == 2) ? (15 - i) : i;
  const int h      = hk * 4 + hs;
  const int q0     = qt * QT;

  const _Float16* kfb = kf + ((size_t)(b * HKV + hk)) * SQ * DH;
  const char*     vtb = (const char*)(vt + ((size_t)(b * HKV + hk)) * 64 * DH * 32);

  // ---- Q fragments (A-layout): row=lm, k=lg*8+j per 32-wide kb ----
  f16x8 qa[4];
  {
    const int qrow = q0 + wv * 16 + lm;
    const float* qp = Q + (((size_t)b * SQ + qrow) * HQ + h) * DH;
    #pragma unroll
    for (int kb = 0; kb < 4; ++kb) {
      const float* p = qp + kb * 32 + lg * 8;
      f32x4 x0 = *(const f32x4*)p;
      f32x4 x1 = *(const f32x4*)(p + 4);
      f16x8 a;
      #pragma unroll
      for (int jj = 0; jj < 4; ++jj) { a[jj] = (_Float16)x0[jj]; a[4 + jj] = (_Float16)x1[jj]; }
      qa[kb] = a;
    }
  }

  const int kmin = (q0 - WIN) > 0 ? (q0 - WIN) : 0;   // multiple of 64
  const int nt   = (q0 + QT - kmin) / KT;             // 1..17
  const int qr0  = q0 + wv * 16 + lg * 4;

  #define STAGE16K(dstb, src) do {                                           \
    _Pragma("unroll")                                                        \
    for (int r4 = 0; r4 < 4; ++r4)                                           \
      gload16((const char*)(src) + r4 * 4096 + wv * 1024 + lane * 16,        \
              (char*)lbuf + (dstb) + r4 * 4096 + wv * 1024);                 \
  } while (0)
  #define STAGE8K(dstb, src) do {                                            \
    _Pragma("unroll")                                                        \
    for (int r2 = 0; r2 < 2; ++r2)                                           \
      gload16((const char*)(src) + r2 * 4096 + wv * 1024 + lane * 16,        \
              (char*)lbuf + (dstb) + r2 * 4096 + wv * 1024);                 \
  } while (0)

  // ================= phase 1: row sums Z (KT=64 K ping-pong) =================
  float zs[4] = {0.f, 0.f, 0.f, 0.f};
  {
    STAGE16K(0, kfb + (size_t)kmin * DH);
    __syncthreads();
    for (int t = 0; t < nt; ++t) {
      if (t + 1 < nt) STAGE16K(((t + 1) & 1) * 16384, kfb + (size_t)(kmin + (t + 1) * KT) * DH);
      const char* cur  = (const char*)lbuf + (t & 1) * 16384;
      const int  kbase = kmin + t * KT;
      const bool peel  = (t == 0 && q0 >= WIN) || (t == nt - 1);
      #pragma unroll
      for (int ks = 0; ks < 4; ++ks) {
        f32x4 acc = {0.f, 0.f, 0.f, 0.f};
        const int keyl = ks * 16 + lm;
        #pragma unroll
        for (int kb = 0; kb < 4; ++kb) {
          const int chunk = (kb * 4 + lg) ^ (keyl & 7);
          f16x8 bf = *(const f16x8*)(cur + keyl * 256 + chunk * 16);
          acc = __builtin_amdgcn_mfma_f32_16x16x32_f16(qa[kb], bf, acc, 0, 0, 0);
        }
        if (peel) {
          const int key = kbase + keyl;
          #pragma unroll
          for (int r = 0; r < 4; ++r) {
            const int qr = qr0 + r;
            const bool ok = (key <= qr) && (key >= qr - WIN);
            zs[r] += ok ? swa_e(acc[r]) : 0.f;
          }
        } else {
          #pragma unroll
          for (int r = 0; r < 4; ++r) zs[r] += swa_e(acc[r]);
        }
      }
      __syncthreads();
    }
  }

  // ---- Z reduce; rz = 1.06/Z; sthr = survivor threshold in s-space ----
  float rz[4], sthr[4];
  #pragma unroll
  for (int r = 0; r < 4; ++r) {
    float z = zs[r];
    z += __shfl_xor(z, 1);
    z += __shfl_xor(z, 2);
    z += __shfl_xor(z, 4);
    z += __shfl_xor(z, 8);
    rz[r] = 1.06f / z;
    float lt = __log2f(0.0283018868f * z);
    float A  = -86.5617024533378f / lt - 1.0f;
    float sv = 3.9204912f * __log2f(A) - 0.05f;   // conservative margin
    sv = (lt >= 0.f) ? 1e30f : sv;
    sv = (lt <= -86.5617f) ? -1e30f : sv;
    sthr[r] = sv;
  }

  // ====== phase 2: weights + PV, KT=32 double-buffered K and V ======
  // lbuf bytes: K0 @0, K1 @8192, V0 @16384, V1 @24576
  f32x4 oacc[8];
  #pragma unroll
  for (int ii = 0; ii < 8; ++ii) oacc[ii] = (f32x4){0.f, 0.f, 0.f, 0.f};

  const int nt2 = (q0 + QT - kmin) >> 5;   // 32-key sub-tiles
  STAGE8K(0,     kfb + (size_t)kmin * DH);
  STAGE8K(16384, vtb + (size_t)(kmin >> 5) * 8192);
  __syncthreads();

  const int vpc = lg ^ ((lm >> 1) & 3);    // physical V chunk for this lane

  for (int t2 = 0; t2 < nt2; ++t2) {
    if (t2 + 1 < nt2) {
      const int kn = kmin + (t2 + 1) * 32;
      STAGE8K(((t2 + 1) & 1) * 8192,         kfb + (size_t)kn * DH);
      STAGE8K(16384 + ((t2 + 1) & 1) * 8192, vtb + (size_t)(kn >> 5) * 8192);
    }
    const char* curK = (const char*)lbuf + (t2 & 1) * 8192;
    const char* curV = (const char*)lbuf + 16384 + (t2 & 1) * 8192;
    const int  kbase = kmin + t2 * 32;
    const bool peel  = ((q0 >= WIN) && (t2 <= 1)) || (t2 >= nt2 - 2);

    #pragma unroll
    for (int ks = 0; ks < 2; ++ks) {
      f32x4 acc = {0.f, 0.f, 0.f, 0.f};
      const int keyl = ks * 16 + lm;
      #pragma unroll
      for (int kb = 0; kb < 4; ++kb) {
        const int chunk = (kb * 4 + lg) ^ (keyl & 7);
        f16x8 bf = *(const f16x8*)(curK + keyl * 256 + chunk * 16);
        acc = __builtin_amdgcn_mfma_f32_16x16x32_f16(qa[kb], bf, acc, 0, 0, 0);
      }
      const int key = kbase + keyl;
      #pragma unroll
      for (int r = 0; r < 4; ++r) {
        float w = 0.f;
        if (__any(acc[r] > sthr[r])) {
          float e = swa_e(acc[r]);
          w = fminf(fmaxf(fmaf(e, rz[r], -0.03f), 0.f), 1.f);
          if (peel) {
            const int qr = qr0 + r;
            const bool ok = (key <= qr) && (key >= qr - WIN);
            w = ok ? w : 0.f;
          }
        }
        lW[wv][(lg * 4 + r) * WROW + ks * 16 + lm] = (_Float16)w;
      }
    }
    // PV over 32 keys: A = W rows, B = V sub-tile rows [d][32], chunk-swizzled
    const f16x8 af = *(const f16x8*)&lW[wv][lm * WROW + lg * 8];
    #pragma unroll
    for (int dt = 0; dt < 8; ++dt) {
      const int d = dt * 16 + lm;
      f16x8 bf = *(const f16x8*)(curV + d * 64 + vpc * 16);
      oacc[dt] = __builtin_amdgcn_mfma_f32_16x16x32_f16(af, bf, oacc[dt], 0, 0, 0);
    }
    __syncthreads();
  }

  // ---- epilogue: D-layout (col=lm is d, row=lg*4+r) -> fp32 out ----
  #pragma unroll
  for (int r = 0; r < 4; ++r) {
    float* op = O + (((size_t)b * SQ + (qr0 + r)) * HQ + h) * DH;
    #pragma unroll
    for (int dt = 0; dt < 8; ++dt) op[dt * 16 + lm] = oacc[dt][r];
  }
  #undef STAGE16K
  #undef STAGE8K
}

extern "C" void kernel_launch(void* const* d_in, const int* in_sizes, int n_in,
                              void* d_out, int out_size, void* d_ws, size_t ws_size,
                              hipStream_t stream) {
  const float* q = (const float*)d_in[0];
  const float* k = (const float*)d_in[1];
  const float* v = (const float*)d_in[2];
  float* o = (float*)d_out;

  _Float16* kf = (_Float16*)d_ws;
  _Float16* vt = kf + (size_t)2 * HKV * SQ * DH;   // 2,097,152 elems each

  hipLaunchKernelGGL(prep, dim3(2048), dim3(256), 0, stream, k, v, kf, vt);
  hipLaunchKernelGGL(swa_fwd, dim3(1024), dim3(256), 0, stream, q, o, kf, vt);
}